// Round 1
// baseline (81.716 us; speedup 1.0000x reference)
//
#include <hip/hip_runtime.h>

#define OUT_STRIDE 576   // IN_F(512) + OUT_F(64)

typedef __attribute__((ext_vector_type(8))) short bf16x8;
typedef __attribute__((ext_vector_type(4))) float f32x4;
typedef _Float16 f16x2 __attribute__((ext_vector_type(2)));

__device__ inline unsigned short f2bf(float f) {
    unsigned u = __float_as_uint(f);
    u = (u + 0x7FFFu + ((u >> 16) & 1u)) >> 16;   // RNE
    return (unsigned short)u;
}

__device__ inline f16x2 b2h(unsigned u) { return __builtin_bit_cast(f16x2, u); }
__device__ inline unsigned short f2h(float f) {
    return __builtin_bit_cast(unsigned short, (_Float16)f);
}

// ---------------- Kernel P: transpose+convert T [512 k][1024 n] fp32 -> Tb [1024 n][512 k] bf16
__global__ __launch_bounds__(256) void transpose_T_kernel(
    const float* __restrict__ T, unsigned short* __restrict__ Tb)
{
    __shared__ float tt[64][68];   // 64x64 tile, pad to 68 (16B-aligned float4 rows)
    const int b = blockIdx.x;      // 128 blocks: 8 k-tiles x 16 n-tiles
    const int t = threadIdx.x;
    const int k0 = (b & 7) * 64, n0 = (b >> 3) * 64;
    const int n4 = (t & 15) * 4, kr = t >> 4;
#pragma unroll
    for (int rr = 0; rr < 4; ++rr) {
        const int k = rr * 16 + kr;
        *(float4*)&tt[k][n4] = *(const float4*)(T + (size_t)(k0 + k) * 1024 + n0 + n4);
    }
    __syncthreads();
#pragma unroll
    for (int q = 0; q < 4; ++q) {
        const int g = q * 256 + t;
        const int nn = g >> 4, c = g & 15;
        ushort4 w;
        w.x = f2bf(tt[c * 4 + 0][nn]);
        w.y = f2bf(tt[c * 4 + 1][nn]);
        w.z = f2bf(tt[c * 4 + 2][nn]);
        w.w = f2bf(tt[c * 4 + 3][nn]);
        *(ushort4*)(Tb + (size_t)(n0 + nn) * 512 + k0 + c * 4) = w;
    }
}

// ---------------- Kernel G: M = x @ T via bf16 MFMA 16x16x32; M stored as f16; + out init ----
__global__ __launch_bounds__(256) void gemm_kernel(
    const float* __restrict__ x, const unsigned short* __restrict__ Tb,
    unsigned short* __restrict__ M16, float* __restrict__ out)
{
    __shared__ unsigned short As[32 * 72];   // [m][k] pad 72
    __shared__ unsigned short Bs[64 * 72];   // [n][k] pad 72
    const int t = threadIdx.x;
    const int bx = blockIdx.x & 15, by = blockIdx.x >> 4;
    const int c0 = bx * 64, r0 = by * 32;
    const int lane = t & 63, w = t >> 6;
    const int m0 = (w >> 1) * 16, nb = (w & 1) * 32;
    const int fl = lane & 15, q8 = (lane >> 4) * 8;
    const int arow = t >> 3, k8 = (t & 7) * 8;

    f32x4 acc0 = {0.f, 0.f, 0.f, 0.f}, acc1 = {0.f, 0.f, 0.f, 0.f};

    for (int kc = 0; kc < 512; kc += 64) {
        {
            const float4 u = *(const float4*)(x + (size_t)(r0 + arow) * 512 + kc + k8);
            const float4 v = *(const float4*)(x + (size_t)(r0 + arow) * 512 + kc + k8 + 4);
            ushort4 w0, w1;
            w0.x = f2bf(u.x); w0.y = f2bf(u.y); w0.z = f2bf(u.z); w0.w = f2bf(u.w);
            w1.x = f2bf(v.x); w1.y = f2bf(v.y); w1.z = f2bf(v.z); w1.w = f2bf(v.w);
            *(ushort4*)&As[arow * 72 + k8] = w0;
            *(ushort4*)&As[arow * 72 + k8 + 4] = w1;
        }
#pragma unroll
        for (int h = 0; h < 2; ++h) {
            const int n = arow + h * 32;
            *(uint4*)&Bs[n * 72 + k8] =
                *(const uint4*)(Tb + (size_t)(c0 + n) * 512 + kc + k8);
        }
        __syncthreads();
        const bf16x8 a0  = *(const bf16x8*)&As[(m0 + fl) * 72 + q8];
        const bf16x8 a1  = *(const bf16x8*)&As[(m0 + fl) * 72 + 32 + q8];
        const bf16x8 b00 = *(const bf16x8*)&Bs[(nb + fl) * 72 + q8];
        const bf16x8 b01 = *(const bf16x8*)&Bs[(nb + fl) * 72 + 32 + q8];
        const bf16x8 b10 = *(const bf16x8*)&Bs[(nb + 16 + fl) * 72 + q8];
        const bf16x8 b11 = *(const bf16x8*)&Bs[(nb + 16 + fl) * 72 + 32 + q8];
        acc0 = __builtin_amdgcn_mfma_f32_16x16x32_bf16(a0, b00, acc0, 0, 0, 0);
        acc0 = __builtin_amdgcn_mfma_f32_16x16x32_bf16(a1, b01, acc0, 0, 0, 0);
        acc1 = __builtin_amdgcn_mfma_f32_16x16x32_bf16(a0, b10, acc1, 0, 0, 0);
        acc1 = __builtin_amdgcn_mfma_f32_16x16x32_bf16(a1, b11, acc1, 0, 0, 0);
        __syncthreads();
    }
    // C/D layout: col = lane&15, row = (lane>>4)*4 + reg; store as f16
    const int orow = r0 + m0 + (lane >> 4) * 4;
#pragma unroll
    for (int r = 0; r < 4; ++r) {
        M16[(size_t)(orow + r) * 1024 + c0 + nb + fl]      = f2h(acc0[r]);
        M16[(size_t)(orow + r) * 1024 + c0 + nb + 16 + fl] = f2h(acc1[r]);
    }

    // ---- epilogue: copy x into out (exact fp32 passthrough) ----
    const int bid = blockIdx.x;    // 0..255
    {
        const int idx = (bid * 256 + t) * 4;
        const int i = idx >> 9, c = idx & 511;
        *(float4*)(out + (size_t)i * OUT_STRIDE + c) = *(const float4*)(x + idx);
    }
    // ---- init o_b region to -1 (cancels self-pair exp(0)=1) ----
    if (t < 128) {
        const int idx = bid * 128 + t;
        const int i = idx >> 6, o = idx & 63;
        out[(size_t)i * OUT_STRIDE + 512 + o] = -1.0f;
    }
}

// ---------------- Kernel B: symmetric pairwise L1 -> exp -> scatter to both sides ----
// Triangle of 16x16 row-tiles: 528 blocks (it <= jc). Thread = (4 i-rows, 1 o).
// l1 = 2*Sum(max(a,b)) - Si - Sj with packed f16 (v_pk_max/v_pk_add = 1 op/elem).
// Si/Sj/Smax use bit-identical chains so the self-pair yields exp(0)=1 exactly
// (cancelled by the -1 init). Off-diagonal tiles also accumulate the j-side via an
// LDS cross-wave reduce, then one atomicAdd per (j,o).
__global__ __launch_bounds__(256) void pairwise_kernel(
    const unsigned short* __restrict__ M16, float* __restrict__ out)
{
    __shared__ unsigned short sj[16 * 1024];   // 32 KB: [j][kh][o][8] halfs, uniform 8/bank
    float* red = (float*)sj;                   // alias: j-side reduce buffer (16 KB)

    const int t = threadIdx.x;
    // decode blockIdx -> (it, jc) with it <= jc, b = jc(jc+1)/2 + it
    int b = blockIdx.x;
    int jc = (int)((sqrtf(8.f * (float)b + 1.f) - 1.f) * 0.5f);
    while ((jc + 1) * (jc + 2) / 2 <= b) ++jc;
    while (jc * (jc + 1) / 2 > b) --jc;
    const int it = b - jc * (jc + 1) / 2;
    const int i0 = it * 16, j0 = jc * 16;
    const bool diag = (it == jc);

    const int o = t & 63, ig = t >> 6;

    // ---- stage j-tile into LDS: 16 rows x 1024 halfs, layout [j][kh][o][8] ----
#pragma unroll
    for (int p = 0; p < 8; ++p) {
        const int g = p * 256 + t;
        const int j = g >> 7, c = g & 127;       // c: 128 x 16B chunks per row
        const int oo = c >> 1, kh = c & 1;
        *(uint4*)&sj[((j * 2 + kh) * 64 + oo) * 8] =
            *(const uint4*)(M16 + (size_t)(j0 + j) * 1024 + c * 8);
    }

    // ---- own 4 i-rows into registers (f16x2 pairs) + Si via canonical chain ----
    f16x2 mi[4][8];
    float SiF[4];
#pragma unroll
    for (int r = 0; r < 4; ++r) {
        const unsigned short* rp = M16 + (size_t)(i0 + ig * 4 + r) * 1024 + o * 16;
        const uint4 u0 = *(const uint4*)rp;
        const uint4 u1 = *(const uint4*)(rp + 8);
        mi[r][0] = b2h(u0.x); mi[r][1] = b2h(u0.y);
        mi[r][2] = b2h(u0.z); mi[r][3] = b2h(u0.w);
        mi[r][4] = b2h(u1.x); mi[r][5] = b2h(u1.y);
        mi[r][6] = b2h(u1.z); mi[r][7] = b2h(u1.w);
        f16x2 s = mi[r][0];
#pragma unroll
        for (int p = 1; p < 8; ++p) s += mi[r][p];
        SiF[r] = (float)s.x + (float)s.y;
    }

    float acc[4] = {0.f, 0.f, 0.f, 0.f};
    float accj[16];
#pragma unroll
    for (int j = 0; j < 16; ++j) accj[j] = 0.f;

    __syncthreads();

#pragma unroll
    for (int j = 0; j < 16; ++j) {
        const unsigned short* sp = &sj[(j * 2) * 512 + o * 8];
        const uint4 w0 = *(const uint4*)sp;           // kh=0: halfs 0..7
        const uint4 w1 = *(const uint4*)(sp + 512);   // kh=1: halfs 8..15
        const f16x2 vj[8] = {b2h(w0.x), b2h(w0.y), b2h(w0.z), b2h(w0.w),
                             b2h(w1.x), b2h(w1.y), b2h(w1.z), b2h(w1.w)};
        f16x2 sv = vj[0];
#pragma unroll
        for (int p = 1; p < 8; ++p) sv += vj[p];
        const float SjF = (float)sv.x + (float)sv.y;
#pragma unroll
        for (int r = 0; r < 4; ++r) {
            f16x2 m2 = __builtin_elementwise_max(mi[r][0], vj[0]);
#pragma unroll
            for (int p = 1; p < 8; ++p)
                m2 += __builtin_elementwise_max(mi[r][p], vj[p]);
            const float SmaxF = (float)m2.x + (float)m2.y;
            // sim = exp(Si + Sj - 2*Smax); self-pair => exactly exp(0) = 1
            const float arg = __builtin_fmaf(SmaxF, -2.f, SiF[r] + SjF);
            const float e = __expf(arg);
            acc[r] += e;
            accj[j] += e;
        }
    }

    // ---- i-side scatter ----
#pragma unroll
    for (int r = 0; r < 4; ++r)
        atomicAdd(out + (size_t)(i0 + ig * 4 + r) * OUT_STRIDE + 512 + o, acc[r]);

    // ---- j-side scatter (off-diagonal tiles only): reduce 4 waves in LDS ----
    if (!diag) {
        __syncthreads();   // all reads of sj done; reuse as reduce buffer
#pragma unroll
        for (int j = 0; j < 16; ++j) red[(ig * 16 + j) * 64 + o] = accj[j];
        __syncthreads();
#pragma unroll
        for (int k = 0; k < 4; ++k) {
            const int e = k * 256 + t;
            const int j = e >> 6, oo = e & 63;
            const float v = red[(0 * 16 + j) * 64 + oo] + red[(1 * 16 + j) * 64 + oo]
                          + red[(2 * 16 + j) * 64 + oo] + red[(3 * 16 + j) * 64 + oo];
            atomicAdd(out + (size_t)(j0 + j) * OUT_STRIDE + 512 + oo, v);
        }
    }
}

extern "C" void kernel_launch(void* const* d_in, const int* in_sizes, int n_in,
                              void* d_out, int out_size, void* d_ws, size_t ws_size,
                              hipStream_t stream) {
    const float* x = (const float*)d_in[0];
    const float* T = (const float*)d_in[1];
    float* out = (float*)d_out;
    unsigned short* M16 = (unsigned short*)d_ws;                      // 1 MB f16
    unsigned short* Tb = (unsigned short*)((char*)d_ws + (2 << 20));  // 1 MB bf16

    transpose_T_kernel<<<128, 256, 0, stream>>>(T, Tb);
    gemm_kernel<<<256, 256, 0, stream>>>(x, Tb, M16, out);
    pairwise_kernel<<<528, 256, 0, stream>>>(M16, out);
}